// Round 9
// baseline (80.648 us; speedup 1.0000x reference)
//
#include <hip/hip_runtime.h>
#include <hip/hip_bf16.h>
#include <limits.h>

// Problem constants (from reference)
#define BB   4
#define NN   2048
#define CC   512
#define TSZ  9
#define TSTEP 6
#define TCUT 2
#define GRIDW 120
#define CMS  132                          // padded cellmap stride (rows & cols)
#define CMSZ (CMS * CMS)                  // per-batch padded cells
#define TILE_ELEMS (CC * TSZ * TSZ)       // 41472
#define OUT_PER_TILE (TILE_ELEMS + 1)     // 41473 (f_ns entry + tile)
#define TI_STRIDE 448                     // per-batch tileinfo stride (>= 441)

typedef float f32x4 __attribute__((ext_vector_type(4)));   // native vec for nontemporal

// ---------------- Kernel 1: per-batch setup (init + scatter + bbox + select) ----------------
// grid = 4 blocks (one per batch), 512 threads. Batches are fully independent:
// block b touches only batch b's cellmap slab. nT <= 441 < 512 -> single pass.
// Produces: tinfo[b*448+j] = (gy0<<8)|gx0 (row-major order) and counts[b].
__global__ __launch_bounds__(512) void setup_kernel(
        const int* __restrict__ ys, const int* __restrict__ xs,
        int* __restrict__ cellmap, int* __restrict__ tinfo,
        int* __restrict__ counts) {
    const int b = blockIdx.x;
    const int tid = threadIdx.x;
    const int lane = tid & 63;
    const int wid = tid >> 6;
    __shared__ int s_red[8][4];
    __shared__ int s_bbox[4];
    __shared__ int s_wave[8];

    int* __restrict__ cm = cellmap + b * CMSZ;

    // init this batch's padded slab to -1
    int4* __restrict__ cm4 = (int4*)cm;
    for (int i = tid; i < CMSZ / 4; i += 512) cm4[i] = make_int4(-1, -1, -1, -1);
    __syncthreads();

    // scatter + bbox in one pass over this batch's points
    int ymin = INT_MAX, ymax = INT_MIN, xmin = INT_MAX, xmax = INT_MIN;
    for (int j = tid; j < NN; j += 512) {
        int y = ys[b * NN + j], x = xs[b * NN + j];
        if (y > -1) {                      // reference filters ys > -1
            cm[y * CMS + x] = j;
            ymin = min(ymin, y); ymax = max(ymax, y);
            xmin = min(xmin, x); xmax = max(xmax, x);
        }
    }
    #pragma unroll
    for (int off = 32; off; off >>= 1) {
        ymin = min(ymin, __shfl_xor(ymin, off));
        ymax = max(ymax, __shfl_xor(ymax, off));
        xmin = min(xmin, __shfl_xor(xmin, off));
        xmax = max(xmax, __shfl_xor(xmax, off));
    }
    if (lane == 0) {
        s_red[wid][0] = ymin; s_red[wid][1] = ymax;
        s_red[wid][2] = xmin; s_red[wid][3] = xmax;
    }
    __syncthreads();                       // also orders scatter stores before select reads
    if (tid == 0) {
        int a = INT_MAX, e = INT_MIN, c = INT_MAX, d = INT_MIN;
        for (int w = 0; w < 8; ++w) {
            a = min(a, s_red[w][0]); e = max(e, s_red[w][1]);
            c = min(c, s_red[w][2]); d = max(d, s_red[w][3]);
        }
        s_bbox[0] = a; s_bbox[1] = e; s_bbox[2] = c; s_bbox[3] = d;
    }
    __syncthreads();
    ymin = s_bbox[0]; ymax = s_bbox[1]; xmin = s_bbox[2]; xmax = s_bbox[3];

    int nH = (ymax - ymin + 1) / TSTEP + 1;   // (H - T_SZ)//T_STEP + 1
    int nW = (xmax - xmin + 1) / TSTEP + 1;
    int nT = nH * nW;                          // <= 441 < 512: single pass

    bool m = false;
    int gy0 = 0, gx0 = 0;
    if (tid < nT) {
        int ti = tid / nW, tj = tid - ti * nW;
        gy0 = ymin + ti * TSTEP;
        gx0 = xmin + tj * TSTEP;
        // center 5x5: 25 independent loads (padded map -> no bounds checks)
        const int* __restrict__ bp = cm + (gy0 + TCUT) * CMS + (gx0 + TCUT);
        int acc = -1;
        #pragma unroll
        for (int dy = 0; dy < 5; ++dy)
            #pragma unroll
            for (int dx = 0; dx < 5; ++dx)
                acc = max(acc, bp[dy * CMS + dx]);
        m = (acc >= 0);
    }
    unsigned long long bal = __ballot(m);
    int lpre = __popcll(bal & ((1ull << lane) - 1ull));
    if (lane == 0) s_wave[wid] = (int)__popcll(bal);
    __syncthreads();
    if (tid == 0) {
        int acc = 0;
        for (int w = 0; w < 8; ++w) { int v = s_wave[w]; s_wave[w] = acc; acc += v; }
        counts[b] = acc;
    }
    __syncthreads();
    if (m) tinfo[b * TI_STRIDE + s_wave[wid] + lpre] = (gy0 << 8) | gx0;
}

// ---------------- Kernel 2: fill output tiles (pipelined gather -> LDS -> stream) ----------------
// One block per tile, 256 threads, 8x 64-channel chunks. Next chunk's gather is
// issued into registers while the current chunk streams LDS->global (latency hidden).
__global__ __launch_bounds__(256) void fill_kernel(
        const float* __restrict__ feats, const int* __restrict__ cellmap,
        const int* __restrict__ tinfo, const int* __restrict__ counts,
        float* __restrict__ f_ns, float* __restrict__ out_tiles) {
    __shared__ int s_list[81];            // compact occupied list: (n<<7)|ce
    __shared__ int s_wcnt[2];
    __shared__ int s_cnt;
    __shared__ __align__(16) float s_f[64 * 81];   // flat == output order, 20.7 KB

    const int tid = threadIdx.x;
    const int lane = tid & 63;
    const int wid = tid >> 6;
    const int k = blockIdx.x;

    // locate batch via 4-int prefix (batch-major global order)
    int c0 = counts[0], c1 = counts[1], c2 = counts[2];
    int b, base;
    if (k < c0)                { b = 0; base = 0; }
    else if (k < c0 + c1)      { b = 1; base = c0; }
    else if (k < c0 + c1 + c2) { b = 2; base = c0 + c1; }
    else                       { b = 3; base = c0 + c1 + c2; }
    const int info = tinfo[b * TI_STRIDE + (k - base)];
    const int gy0 = info >> 8, gx0 = info & 255;
    if (tid == 0) f_ns[k] = (float)b;

    // zero the chunk buffer once; unoccupied cells stay 0 across all chunks
    const float4 z = make_float4(0.f, 0.f, 0.f, 0.f);
    for (int f4 = tid; f4 < 1296; f4 += 256) ((float4*)s_f)[f4] = z;

    int n = -1;
    if (tid < 81) {
        int r = tid / 9, c = tid - r * 9;
        n = cellmap[b * CMSZ + (gy0 + r) * CMS + (gx0 + c)];
    }
    bool occ = (tid < 81) && (n >= 0);
    unsigned long long bal = __ballot(occ);
    int pre = __popcll(bal & ((1ull << lane) - 1ull));
    if (lane == 0 && wid < 2) s_wcnt[wid] = (int)__popcll(bal);
    __syncthreads();
    if (occ) s_list[(wid == 1 ? s_wcnt[0] : 0) + pre] = (n << 7) | tid;
    if (tid == 0) s_cnt = s_wcnt[0] + s_wcnt[1];
    __syncthreads();

    const int nk = s_cnt;
    const int items = nk * 16;            // float4 gathers per chunk
    const float* __restrict__ fb = feats + (size_t)b * (NN * CC);
    float* __restrict__ outk = out_tiles + (size_t)k * TILE_ELEMS;

    if (items <= 512) {
        // fast path: <= 2 gather-registers per thread, software-pipelined
        const bool h0 = tid < items, h1 = tid + 256 < items;
        const float* p0 = fb; const float* p1 = fb;
        int d0 = 0, d1 = 0;
        if (h0) { int pk = s_list[tid >> 4], q = tid & 15;
                  p0 = fb + (pk >> 7) * CC + q * 4; d0 = q * 324 + (pk & 127); }
        if (h1) { int e = tid + 256; int pk = s_list[e >> 4], q = e & 15;
                  p1 = fb + (pk >> 7) * CC + q * 4; d1 = q * 324 + (pk & 127); }
        float4 g0, g1;
        if (h0) g0 = *(const float4*)p0;
        if (h1) g1 = *(const float4*)p1;
        #pragma unroll 1
        for (int c = 0; c < 8; ++c) {
            // commit in-flight gathers to LDS (vmcnt wait inserted here)
            if (h0) { s_f[d0] = g0.x; s_f[d0+81] = g0.y; s_f[d0+162] = g0.z; s_f[d0+243] = g0.w; }
            if (h1) { s_f[d1] = g1.x; s_f[d1+81] = g1.y; s_f[d1+162] = g1.z; s_f[d1+243] = g1.w; }
            __syncthreads();
            // issue next chunk's gathers; they fly under the store stream below
            if (c < 7) {
                if (h0) { p0 += 64; g0 = *(const float4*)p0; }
                if (h1) { p1 += 64; g1 = *(const float4*)p1; }
            }
            // stream chunk c: 1296 float4, conflict-free ds_read_b128, nt stores
            float* __restrict__ outc = outk + c * (64 * 81);
            #pragma unroll
            for (int it = 0; it < 6; ++it) {
                int idx = it * 256 + tid;
                if (idx < 1296) {
                    f32x4 v = ((const f32x4*)s_f)[idx];
                    __builtin_nontemporal_store(v, (f32x4*)outc + idx);
                }
            }
            __syncthreads();
        }
    } else {
        // rare dense-tile fallback (nk > 32): unpipelined
        for (int c = 0; c < 8; ++c) {
            for (int e = tid; e < items; e += 256) {
                int pk = s_list[e >> 4], q = e & 15;
                float4 v = *(const float4*)(fb + (pk >> 7) * CC + c * 64 + q * 4);
                int d = q * 324 + (pk & 127);
                s_f[d] = v.x; s_f[d+81] = v.y; s_f[d+162] = v.z; s_f[d+243] = v.w;
            }
            __syncthreads();
            float* __restrict__ outc = outk + c * (64 * 81);
            for (int f4 = tid; f4 < 1296; f4 += 256) {
                f32x4 v = ((const f32x4*)s_f)[f4];
                __builtin_nontemporal_store(v, (f32x4*)outc + f4);
            }
            __syncthreads();
        }
    }
}

extern "C" void kernel_launch(void* const* d_in, const int* in_sizes, int n_in,
                              void* d_out, int out_size, void* d_ws, size_t ws_size,
                              hipStream_t stream) {
    const float* feats = (const float*)d_in[0];
    const int* ys = (const int*)d_in[1];
    const int* xs = (const int*)d_in[2];
    float* out = (float*)d_out;

    char* ws = (char*)d_ws;
    int* cellmap = (int*)ws;                              // 4*132*132*4 = 278784 B
    int* tinfo = (int*)(ws + BB * CMSZ * 4);              // 4*448 ints = 7168 B
    int* counts = (int*)(ws + BB * CMSZ * 4 + BB * TI_STRIDE * 4);  // 4 ints

    const int K = out_size / OUT_PER_TILE;                // number of selected tiles
    float* f_ns = out;                                    // first K floats
    float* out_tiles = out + K;                           // K * 41472 floats

    setup_kernel<<<BB, 512, 0, stream>>>(ys, xs, cellmap, tinfo, counts);
    fill_kernel<<<K, 256, 0, stream>>>(feats, cellmap, tinfo, counts, f_ns, out_tiles);
}

// Round 10
// 61.732 us; speedup vs baseline: 1.3064x; 1.3064x over previous
//
#include <hip/hip_runtime.h>
#include <hip/hip_bf16.h>
#include <limits.h>

// Problem constants (from reference)
#define BB   4
#define NN   2048
#define CC   512
#define TSZ  9
#define TSTEP 6
#define TCUT 2
#define GRIDW 120
#define CMS  132                          // padded cellmap stride (rows & cols)
#define CMSZ (CMS * CMS)                  // per-batch padded cells
#define TILE_ELEMS (CC * TSZ * TSZ)       // 41472
#define OUT_PER_TILE (TILE_ELEMS + 1)     // 41473 (f_ns entry + tile)
#define TI_STRIDE 448                     // per-batch tileinfo stride (>= 441)

// ---------------- Kernel 1: per-batch setup (init + scatter + bbox + select) ----------------
// grid = 4 blocks (one per batch), 512 threads. Batches are fully independent:
// block b touches only batch b's cellmap slab. nT <= 441 < 512 -> single pass.
// Produces: tinfo[b*448+j] = (gy0<<8)|gx0 (row-major order) and counts[b].
__global__ __launch_bounds__(512) void setup_kernel(
        const int* __restrict__ ys, const int* __restrict__ xs,
        int* __restrict__ cellmap, int* __restrict__ tinfo,
        int* __restrict__ counts) {
    const int b = blockIdx.x;
    const int tid = threadIdx.x;
    const int lane = tid & 63;
    const int wid = tid >> 6;
    __shared__ int s_red[8][4];
    __shared__ int s_bbox[4];
    __shared__ int s_wave[8];

    int* __restrict__ cm = cellmap + b * CMSZ;

    // init this batch's padded slab to -1
    int4* __restrict__ cm4 = (int4*)cm;
    for (int i = tid; i < CMSZ / 4; i += 512) cm4[i] = make_int4(-1, -1, -1, -1);
    __syncthreads();

    // scatter + bbox in one pass over this batch's points
    int ymin = INT_MAX, ymax = INT_MIN, xmin = INT_MAX, xmax = INT_MIN;
    for (int j = tid; j < NN; j += 512) {
        int y = ys[b * NN + j], x = xs[b * NN + j];
        if (y > -1) {                      // reference filters ys > -1
            cm[y * CMS + x] = j;
            ymin = min(ymin, y); ymax = max(ymax, y);
            xmin = min(xmin, x); xmax = max(xmax, x);
        }
    }
    #pragma unroll
    for (int off = 32; off; off >>= 1) {
        ymin = min(ymin, __shfl_xor(ymin, off));
        ymax = max(ymax, __shfl_xor(ymax, off));
        xmin = min(xmin, __shfl_xor(xmin, off));
        xmax = max(xmax, __shfl_xor(xmax, off));
    }
    if (lane == 0) {
        s_red[wid][0] = ymin; s_red[wid][1] = ymax;
        s_red[wid][2] = xmin; s_red[wid][3] = xmax;
    }
    __syncthreads();                       // also orders scatter stores before select reads
    if (tid == 0) {
        int a = INT_MAX, e = INT_MIN, c = INT_MAX, d = INT_MIN;
        for (int w = 0; w < 8; ++w) {
            a = min(a, s_red[w][0]); e = max(e, s_red[w][1]);
            c = min(c, s_red[w][2]); d = max(d, s_red[w][3]);
        }
        s_bbox[0] = a; s_bbox[1] = e; s_bbox[2] = c; s_bbox[3] = d;
    }
    __syncthreads();
    ymin = s_bbox[0]; ymax = s_bbox[1]; xmin = s_bbox[2]; xmax = s_bbox[3];

    int nH = (ymax - ymin + 1) / TSTEP + 1;   // (H - T_SZ)//T_STEP + 1
    int nW = (xmax - xmin + 1) / TSTEP + 1;
    int nT = nH * nW;                          // <= 441 < 512: single pass

    bool m = false;
    int gy0 = 0, gx0 = 0;
    if (tid < nT) {
        int ti = tid / nW, tj = tid - ti * nW;
        gy0 = ymin + ti * TSTEP;
        gx0 = xmin + tj * TSTEP;
        // center 5x5: 25 independent loads (padded map -> no bounds checks)
        const int* __restrict__ bp = cm + (gy0 + TCUT) * CMS + (gx0 + TCUT);
        int acc = -1;
        #pragma unroll
        for (int dy = 0; dy < 5; ++dy)
            #pragma unroll
            for (int dx = 0; dx < 5; ++dx)
                acc = max(acc, bp[dy * CMS + dx]);
        m = (acc >= 0);
    }
    unsigned long long bal = __ballot(m);
    int lpre = __popcll(bal & ((1ull << lane) - 1ull));
    if (lane == 0) s_wave[wid] = (int)__popcll(bal);
    __syncthreads();
    if (tid == 0) {
        int acc = 0;
        for (int w = 0; w < 8; ++w) { int v = s_wave[w]; s_wave[w] = acc; acc += v; }
        counts[b] = acc;
    }
    __syncthreads();
    if (m) tinfo[b * TI_STRIDE + s_wave[wid] + lpre] = (gy0 << 8) | gx0;
}

// ---------------- Kernel 2: fill output tiles (pipelined gather -> LDS -> stream) ----------------
// One block per tile, 256 threads, 8x 64-channel chunks. Next chunk's gather is
// issued into registers while the current chunk streams LDS->global (latency hidden).
__global__ __launch_bounds__(256) void fill_kernel(
        const float* __restrict__ feats, const int* __restrict__ cellmap,
        const int* __restrict__ tinfo, const int* __restrict__ counts,
        float* __restrict__ f_ns, float* __restrict__ out_tiles) {
    __shared__ int s_list[81];            // compact occupied list: (n<<7)|ce
    __shared__ int s_wcnt[2];
    __shared__ int s_cnt;
    __shared__ __align__(16) float s_f[64 * 81];   // flat == output order, 20.7 KB

    const int tid = threadIdx.x;
    const int lane = tid & 63;
    const int wid = tid >> 6;
    const int k = blockIdx.x;

    // locate batch via 4-int prefix (batch-major global order)
    int c0 = counts[0], c1 = counts[1], c2 = counts[2];
    int b, base;
    if (k < c0)                { b = 0; base = 0; }
    else if (k < c0 + c1)      { b = 1; base = c0; }
    else if (k < c0 + c1 + c2) { b = 2; base = c0 + c1; }
    else                       { b = 3; base = c0 + c1 + c2; }
    const int info = tinfo[b * TI_STRIDE + (k - base)];
    const int gy0 = info >> 8, gx0 = info & 255;
    if (tid == 0) f_ns[k] = (float)b;

    // zero the chunk buffer once; unoccupied cells stay 0 across all chunks
    const float4 z = make_float4(0.f, 0.f, 0.f, 0.f);
    for (int f4 = tid; f4 < 1296; f4 += 256) ((float4*)s_f)[f4] = z;

    int n = -1;
    if (tid < 81) {
        int r = tid / 9, c = tid - r * 9;
        n = cellmap[b * CMSZ + (gy0 + r) * CMS + (gx0 + c)];
    }
    bool occ = (tid < 81) && (n >= 0);
    unsigned long long bal = __ballot(occ);
    int pre = __popcll(bal & ((1ull << lane) - 1ull));
    if (lane == 0 && wid < 2) s_wcnt[wid] = (int)__popcll(bal);
    __syncthreads();
    if (occ) s_list[(wid == 1 ? s_wcnt[0] : 0) + pre] = (n << 7) | tid;
    if (tid == 0) s_cnt = s_wcnt[0] + s_wcnt[1];
    __syncthreads();

    const int nk = s_cnt;
    const int items = nk * 16;            // float4 gathers per chunk
    const float* __restrict__ fb = feats + (size_t)b * (NN * CC);
    float* __restrict__ outk = out_tiles + (size_t)k * TILE_ELEMS;

    if (items <= 512) {
        // fast path: <= 2 gather-registers per thread, software-pipelined
        const bool h0 = tid < items, h1 = tid + 256 < items;
        const float* p0 = fb; const float* p1 = fb;
        int d0 = 0, d1 = 0;
        if (h0) { int pk = s_list[tid >> 4], q = tid & 15;
                  p0 = fb + (pk >> 7) * CC + q * 4; d0 = q * 324 + (pk & 127); }
        if (h1) { int e = tid + 256; int pk = s_list[e >> 4], q = e & 15;
                  p1 = fb + (pk >> 7) * CC + q * 4; d1 = q * 324 + (pk & 127); }
        float4 g0, g1;
        if (h0) g0 = *(const float4*)p0;
        if (h1) g1 = *(const float4*)p1;
        #pragma unroll 1
        for (int c = 0; c < 8; ++c) {
            // commit in-flight gathers to LDS (vmcnt wait inserted here)
            if (h0) { s_f[d0] = g0.x; s_f[d0+81] = g0.y; s_f[d0+162] = g0.z; s_f[d0+243] = g0.w; }
            if (h1) { s_f[d1] = g1.x; s_f[d1+81] = g1.y; s_f[d1+162] = g1.z; s_f[d1+243] = g1.w; }
            __syncthreads();
            // issue next chunk's gathers; they fly under the store stream below
            if (c < 7) {
                if (h0) { p0 += 64; g0 = *(const float4*)p0; }
                if (h1) { p1 += 64; g1 = *(const float4*)p1; }
            }
            // stream chunk c: 1296 float4, conflict-free ds_read_b128, coalesced stores
            float* __restrict__ outc = outk + c * (64 * 81);
            #pragma unroll
            for (int it = 0; it < 6; ++it) {
                int idx = it * 256 + tid;
                if (idx < 1296) {
                    float4 v = ((const float4*)s_f)[idx];
                    *((float4*)outc + idx) = v;
                }
            }
            __syncthreads();
        }
    } else {
        // rare dense-tile fallback (nk > 32): unpipelined
        for (int c = 0; c < 8; ++c) {
            for (int e = tid; e < items; e += 256) {
                int pk = s_list[e >> 4], q = e & 15;
                float4 v = *(const float4*)(fb + (pk >> 7) * CC + c * 64 + q * 4);
                int d = q * 324 + (pk & 127);
                s_f[d] = v.x; s_f[d+81] = v.y; s_f[d+162] = v.z; s_f[d+243] = v.w;
            }
            __syncthreads();
            float* __restrict__ outc = outk + c * (64 * 81);
            for (int f4 = tid; f4 < 1296; f4 += 256) {
                float4 v = ((const float4*)s_f)[f4];
                *((float4*)outc + f4) = v;
            }
            __syncthreads();
        }
    }
}

extern "C" void kernel_launch(void* const* d_in, const int* in_sizes, int n_in,
                              void* d_out, int out_size, void* d_ws, size_t ws_size,
                              hipStream_t stream) {
    const float* feats = (const float*)d_in[0];
    const int* ys = (const int*)d_in[1];
    const int* xs = (const int*)d_in[2];
    float* out = (float*)d_out;

    char* ws = (char*)d_ws;
    int* cellmap = (int*)ws;                              // 4*132*132*4 = 278784 B
    int* tinfo = (int*)(ws + BB * CMSZ * 4);              // 4*448 ints = 7168 B
    int* counts = (int*)(ws + BB * CMSZ * 4 + BB * TI_STRIDE * 4);  // 4 ints

    const int K = out_size / OUT_PER_TILE;                // number of selected tiles
    float* f_ns = out;                                    // first K floats
    float* out_tiles = out + K;                           // K * 41472 floats

    setup_kernel<<<BB, 512, 0, stream>>>(ys, xs, cellmap, tinfo, counts);
    fill_kernel<<<K, 256, 0, stream>>>(feats, cellmap, tinfo, counts, f_ns, out_tiles);
}

// Round 11
// 60.632 us; speedup vs baseline: 1.3301x; 1.0181x over previous
//
#include <hip/hip_runtime.h>
#include <hip/hip_bf16.h>
#include <limits.h>

// Problem constants (from reference)
#define BB   4
#define NN   2048
#define CC   512
#define TSZ  9
#define TSTEP 6
#define TCUT 2
#define GRIDW 120
#define CMS  132                          // padded cellmap stride (rows & cols)
#define CMSZ (CMS * CMS)                  // per-batch padded cells
#define TILE_ELEMS (CC * TSZ * TSZ)       // 41472
#define OUT_PER_TILE (TILE_ELEMS + 1)     // 41473 (f_ns entry + tile)
#define TI_STRIDE 448                     // per-batch tileinfo stride (>= 441)

// ---------------- Kernel 1: per-batch setup (init + scatter + bbox + select) ----------------
// grid = 4 blocks (one per batch), 512 threads. Batches are fully independent:
// block b touches only batch b's cellmap slab. nT <= 441 < 512 -> single pass.
// Produces: tinfo[b*448+j] = (gy0<<8)|gx0 (row-major order) and counts[b].
__global__ __launch_bounds__(512) void setup_kernel(
        const int* __restrict__ ys, const int* __restrict__ xs,
        int* __restrict__ cellmap, int* __restrict__ tinfo,
        int* __restrict__ counts) {
    const int b = blockIdx.x;
    const int tid = threadIdx.x;
    const int lane = tid & 63;
    const int wid = tid >> 6;
    __shared__ int s_red[8][4];
    __shared__ int s_bbox[4];
    __shared__ int s_wave[8];

    int* __restrict__ cm = cellmap + b * CMSZ;

    // init this batch's padded slab to -1
    int4* __restrict__ cm4 = (int4*)cm;
    for (int i = tid; i < CMSZ / 4; i += 512) cm4[i] = make_int4(-1, -1, -1, -1);
    __syncthreads();

    // scatter + bbox in one pass over this batch's points
    int ymin = INT_MAX, ymax = INT_MIN, xmin = INT_MAX, xmax = INT_MIN;
    for (int j = tid; j < NN; j += 512) {
        int y = ys[b * NN + j], x = xs[b * NN + j];
        if (y > -1) {                      // reference filters ys > -1
            cm[y * CMS + x] = j;
            ymin = min(ymin, y); ymax = max(ymax, y);
            xmin = min(xmin, x); xmax = max(xmax, x);
        }
    }
    #pragma unroll
    for (int off = 32; off; off >>= 1) {
        ymin = min(ymin, __shfl_xor(ymin, off));
        ymax = max(ymax, __shfl_xor(ymax, off));
        xmin = min(xmin, __shfl_xor(xmin, off));
        xmax = max(xmax, __shfl_xor(xmax, off));
    }
    if (lane == 0) {
        s_red[wid][0] = ymin; s_red[wid][1] = ymax;
        s_red[wid][2] = xmin; s_red[wid][3] = xmax;
    }
    __syncthreads();                       // also orders scatter stores before select reads
    if (tid == 0) {
        int a = INT_MAX, e = INT_MIN, c = INT_MAX, d = INT_MIN;
        for (int w = 0; w < 8; ++w) {
            a = min(a, s_red[w][0]); e = max(e, s_red[w][1]);
            c = min(c, s_red[w][2]); d = max(d, s_red[w][3]);
        }
        s_bbox[0] = a; s_bbox[1] = e; s_bbox[2] = c; s_bbox[3] = d;
    }
    __syncthreads();
    ymin = s_bbox[0]; ymax = s_bbox[1]; xmin = s_bbox[2]; xmax = s_bbox[3];

    int nH = (ymax - ymin + 1) / TSTEP + 1;   // (H - T_SZ)//T_STEP + 1
    int nW = (xmax - xmin + 1) / TSTEP + 1;
    int nT = nH * nW;                          // <= 441 < 512: single pass

    bool m = false;
    int gy0 = 0, gx0 = 0;
    if (tid < nT) {
        int ti = tid / nW, tj = tid - ti * nW;
        gy0 = ymin + ti * TSTEP;
        gx0 = xmin + tj * TSTEP;
        // center 5x5: 25 independent loads (padded map -> no bounds checks)
        const int* __restrict__ bp = cm + (gy0 + TCUT) * CMS + (gx0 + TCUT);
        int acc = -1;
        #pragma unroll
        for (int dy = 0; dy < 5; ++dy)
            #pragma unroll
            for (int dx = 0; dx < 5; ++dx)
                acc = max(acc, bp[dy * CMS + dx]);
        m = (acc >= 0);
    }
    unsigned long long bal = __ballot(m);
    int lpre = __popcll(bal & ((1ull << lane) - 1ull));
    if (lane == 0) s_wave[wid] = (int)__popcll(bal);
    __syncthreads();
    if (tid == 0) {
        int acc = 0;
        for (int w = 0; w < 8; ++w) { int v = s_wave[w]; s_wave[w] = acc; acc += v; }
        counts[b] = acc;
    }
    __syncthreads();
    if (m) tinfo[b * TI_STRIDE + s_wave[wid] + lpre] = (gy0 << 8) | gx0;
}

// ---------------- Kernel 2: fill output tiles (pipelined gather -> LDS -> stream) ----------------
// grid = 2K: two blocks per tile, each handling 4 of the 8 64-channel chunks.
// Next chunk's gather is issued into registers while the current chunk streams
// LDS->global (latency hidden under the store stream).
__global__ __launch_bounds__(256) void fill_kernel(
        const float* __restrict__ feats, const int* __restrict__ cellmap,
        const int* __restrict__ tinfo, const int* __restrict__ counts,
        float* __restrict__ f_ns, float* __restrict__ out_tiles) {
    __shared__ int s_list[81];            // compact occupied list: (n<<7)|ce
    __shared__ int s_wcnt[2];
    __shared__ int s_cnt;
    __shared__ __align__(16) float s_f[64 * 81];   // flat == output order, 20.7 KB

    const int tid = threadIdx.x;
    const int lane = tid & 63;
    const int wid = tid >> 6;
    const int k = blockIdx.x >> 1;
    const int h = blockIdx.x & 1;         // which half (chunks 4h .. 4h+3)

    // locate batch via 4-int prefix (batch-major global order)
    int c0 = counts[0], c1 = counts[1], c2 = counts[2];
    int b, base;
    if (k < c0)                { b = 0; base = 0; }
    else if (k < c0 + c1)      { b = 1; base = c0; }
    else if (k < c0 + c1 + c2) { b = 2; base = c0 + c1; }
    else                       { b = 3; base = c0 + c1 + c2; }
    const int info = tinfo[b * TI_STRIDE + (k - base)];
    const int gy0 = info >> 8, gx0 = info & 255;
    if (tid == 0 && h == 0) f_ns[k] = (float)b;

    // zero the chunk buffer once; unoccupied cells stay 0 across all chunks
    const float4 z = make_float4(0.f, 0.f, 0.f, 0.f);
    for (int f4 = tid; f4 < 1296; f4 += 256) ((float4*)s_f)[f4] = z;

    int n = -1;
    if (tid < 81) {
        int r = tid / 9, c = tid - r * 9;
        n = cellmap[b * CMSZ + (gy0 + r) * CMS + (gx0 + c)];
    }
    bool occ = (tid < 81) && (n >= 0);
    unsigned long long bal = __ballot(occ);
    int pre = __popcll(bal & ((1ull << lane) - 1ull));
    if (lane == 0 && wid < 2) s_wcnt[wid] = (int)__popcll(bal);
    __syncthreads();
    if (occ) s_list[(wid == 1 ? s_wcnt[0] : 0) + pre] = (n << 7) | tid;
    if (tid == 0) s_cnt = s_wcnt[0] + s_wcnt[1];
    __syncthreads();

    const int nk = s_cnt;
    const int items = nk * 16;            // float4 gathers per chunk
    const float* __restrict__ fb = feats + (size_t)b * (NN * CC) + h * 256;
    float* __restrict__ outk = out_tiles + (size_t)k * TILE_ELEMS + h * (4 * 64 * 81);

    if (items <= 512) {
        // fast path: <= 2 gather-registers per thread, software-pipelined
        const bool h0 = tid < items, h1 = tid + 256 < items;
        const float* p0 = fb; const float* p1 = fb;
        int d0 = 0, d1 = 0;
        if (h0) { int pk = s_list[tid >> 4], q = tid & 15;
                  p0 = fb + (pk >> 7) * CC + q * 4; d0 = q * 324 + (pk & 127); }
        if (h1) { int e = tid + 256; int pk = s_list[e >> 4], q = e & 15;
                  p1 = fb + (pk >> 7) * CC + q * 4; d1 = q * 324 + (pk & 127); }
        float4 g0, g1;
        if (h0) g0 = *(const float4*)p0;
        if (h1) g1 = *(const float4*)p1;
        #pragma unroll 1
        for (int c = 0; c < 4; ++c) {
            // commit in-flight gathers to LDS (vmcnt wait inserted here)
            if (h0) { s_f[d0] = g0.x; s_f[d0+81] = g0.y; s_f[d0+162] = g0.z; s_f[d0+243] = g0.w; }
            if (h1) { s_f[d1] = g1.x; s_f[d1+81] = g1.y; s_f[d1+162] = g1.z; s_f[d1+243] = g1.w; }
            __syncthreads();
            // issue next chunk's gathers; they fly under the store stream below
            if (c < 3) {
                if (h0) { p0 += 64; g0 = *(const float4*)p0; }
                if (h1) { p1 += 64; g1 = *(const float4*)p1; }
            }
            // stream chunk c: 1296 float4, conflict-free ds_read_b128, coalesced stores
            float* __restrict__ outc = outk + c * (64 * 81);
            #pragma unroll
            for (int it = 0; it < 6; ++it) {
                int idx = it * 256 + tid;
                if (idx < 1296) {
                    float4 v = ((const float4*)s_f)[idx];
                    *((float4*)outc + idx) = v;
                }
            }
            __syncthreads();
        }
    } else {
        // rare dense-tile fallback (nk > 32): unpipelined
        for (int c = 0; c < 4; ++c) {
            for (int e = tid; e < items; e += 256) {
                int pk = s_list[e >> 4], q = e & 15;
                float4 v = *(const float4*)(fb + (pk >> 7) * CC + c * 64 + q * 4);
                int d = q * 324 + (pk & 127);
                s_f[d] = v.x; s_f[d+81] = v.y; s_f[d+162] = v.z; s_f[d+243] = v.w;
            }
            __syncthreads();
            float* __restrict__ outc = outk + c * (64 * 81);
            for (int f4 = tid; f4 < 1296; f4 += 256) {
                float4 v = ((const float4*)s_f)[f4];
                *((float4*)outc + f4) = v;
            }
            __syncthreads();
        }
    }
}

extern "C" void kernel_launch(void* const* d_in, const int* in_sizes, int n_in,
                              void* d_out, int out_size, void* d_ws, size_t ws_size,
                              hipStream_t stream) {
    const float* feats = (const float*)d_in[0];
    const int* ys = (const int*)d_in[1];
    const int* xs = (const int*)d_in[2];
    float* out = (float*)d_out;

    char* ws = (char*)d_ws;
    int* cellmap = (int*)ws;                              // 4*132*132*4 = 278784 B
    int* tinfo = (int*)(ws + BB * CMSZ * 4);              // 4*448 ints = 7168 B
    int* counts = (int*)(ws + BB * CMSZ * 4 + BB * TI_STRIDE * 4);  // 4 ints

    const int K = out_size / OUT_PER_TILE;                // number of selected tiles
    float* f_ns = out;                                    // first K floats
    float* out_tiles = out + K;                           // K * 41472 floats

    setup_kernel<<<BB, 512, 0, stream>>>(ys, xs, cellmap, tinfo, counts);
    fill_kernel<<<K * 2, 256, 0, stream>>>(feats, cellmap, tinfo, counts, f_ns, out_tiles);
}

// Round 12
// 57.969 us; speedup vs baseline: 1.3912x; 1.0459x over previous
//
#include <hip/hip_runtime.h>
#include <hip/hip_bf16.h>
#include <limits.h>

// Problem constants (from reference)
#define BB   4
#define NN   2048
#define CC   512
#define TSZ  9
#define TSTEP 6
#define TCUT 2
#define GRIDW 120
#define CMS  132                          // padded cellmap stride (rows & cols)
#define CMSZ (CMS * CMS)                  // per-batch padded cells
#define TILE_ELEMS (CC * TSZ * TSZ)       // 41472
#define OUT_PER_TILE (TILE_ELEMS + 1)     // 41473 (f_ns entry + tile)
#define TI_STRIDE 448                     // per-batch tileinfo stride (>= 441)

// Barrier WITHOUT the compiler's vmcnt(0) store-drain: only LDS ops are
// ordered (lgkmcnt). Global stores keep streaming across the barrier.
__device__ __forceinline__ void light_barrier() {
    asm volatile("s_waitcnt lgkmcnt(0)" ::: "memory");
    __builtin_amdgcn_s_barrier();
}

// ---------------- Kernel 1: per-batch setup (init + scatter + bbox + select) ----------------
// grid = 4 blocks (one per batch), 512 threads. Batches are fully independent:
// block b touches only batch b's cellmap slab. nT <= 441 < 512 -> single pass.
// Produces: tinfo[b*448+j] = (gy0<<8)|gx0 (row-major order) and counts[b].
__global__ __launch_bounds__(512) void setup_kernel(
        const int* __restrict__ ys, const int* __restrict__ xs,
        int* __restrict__ cellmap, int* __restrict__ tinfo,
        int* __restrict__ counts) {
    const int b = blockIdx.x;
    const int tid = threadIdx.x;
    const int lane = tid & 63;
    const int wid = tid >> 6;
    __shared__ int s_red[8][4];
    __shared__ int s_bbox[4];
    __shared__ int s_wave[8];

    int* __restrict__ cm = cellmap + b * CMSZ;

    // init this batch's padded slab to -1
    int4* __restrict__ cm4 = (int4*)cm;
    for (int i = tid; i < CMSZ / 4; i += 512) cm4[i] = make_int4(-1, -1, -1, -1);
    __syncthreads();

    // scatter + bbox in one pass over this batch's points
    int ymin = INT_MAX, ymax = INT_MIN, xmin = INT_MAX, xmax = INT_MIN;
    for (int j = tid; j < NN; j += 512) {
        int y = ys[b * NN + j], x = xs[b * NN + j];
        if (y > -1) {                      // reference filters ys > -1
            cm[y * CMS + x] = j;
            ymin = min(ymin, y); ymax = max(ymax, y);
            xmin = min(xmin, x); xmax = max(xmax, x);
        }
    }
    #pragma unroll
    for (int off = 32; off; off >>= 1) {
        ymin = min(ymin, __shfl_xor(ymin, off));
        ymax = max(ymax, __shfl_xor(ymax, off));
        xmin = min(xmin, __shfl_xor(xmin, off));
        xmax = max(xmax, __shfl_xor(xmax, off));
    }
    if (lane == 0) {
        s_red[wid][0] = ymin; s_red[wid][1] = ymax;
        s_red[wid][2] = xmin; s_red[wid][3] = xmax;
    }
    __syncthreads();                       // also orders scatter stores before select reads
    if (tid == 0) {
        int a = INT_MAX, e = INT_MIN, c = INT_MAX, d = INT_MIN;
        for (int w = 0; w < 8; ++w) {
            a = min(a, s_red[w][0]); e = max(e, s_red[w][1]);
            c = min(c, s_red[w][2]); d = max(d, s_red[w][3]);
        }
        s_bbox[0] = a; s_bbox[1] = e; s_bbox[2] = c; s_bbox[3] = d;
    }
    __syncthreads();
    ymin = s_bbox[0]; ymax = s_bbox[1]; xmin = s_bbox[2]; xmax = s_bbox[3];

    int nH = (ymax - ymin + 1) / TSTEP + 1;   // (H - T_SZ)//T_STEP + 1
    int nW = (xmax - xmin + 1) / TSTEP + 1;
    int nT = nH * nW;                          // <= 441 < 512: single pass

    bool m = false;
    int gy0 = 0, gx0 = 0;
    if (tid < nT) {
        int ti = tid / nW, tj = tid - ti * nW;
        gy0 = ymin + ti * TSTEP;
        gx0 = xmin + tj * TSTEP;
        // center 5x5: 25 independent loads (padded map -> no bounds checks)
        const int* __restrict__ bp = cm + (gy0 + TCUT) * CMS + (gx0 + TCUT);
        int acc = -1;
        #pragma unroll
        for (int dy = 0; dy < 5; ++dy)
            #pragma unroll
            for (int dx = 0; dx < 5; ++dx)
                acc = max(acc, bp[dy * CMS + dx]);
        m = (acc >= 0);
    }
    unsigned long long bal = __ballot(m);
    int lpre = __popcll(bal & ((1ull << lane) - 1ull));
    if (lane == 0) s_wave[wid] = (int)__popcll(bal);
    __syncthreads();
    if (tid == 0) {
        int acc = 0;
        for (int w = 0; w < 8; ++w) { int v = s_wave[w]; s_wave[w] = acc; acc += v; }
        counts[b] = acc;
    }
    __syncthreads();
    if (m) tinfo[b * TI_STRIDE + s_wave[wid] + lpre] = (gy0 << 8) | gx0;
}

// ---------------- Kernel 2: fill output tiles (pipelined gather -> LDS -> stream) ----------------
// grid = 2K: two blocks per tile, each handling 4 of the 8 64-channel chunks.
// Next chunk's gather is issued into registers while the current chunk streams
// LDS->global. Chunk-loop barriers are lgkmcnt-only (no store-queue drain).
__global__ __launch_bounds__(256) void fill_kernel(
        const float* __restrict__ feats, const int* __restrict__ cellmap,
        const int* __restrict__ tinfo, const int* __restrict__ counts,
        float* __restrict__ f_ns, float* __restrict__ out_tiles) {
    __shared__ int s_list[81];            // compact occupied list: (n<<7)|ce
    __shared__ int s_wcnt[2];
    __shared__ int s_cnt;
    __shared__ __align__(16) float s_f[64 * 81];   // flat == output order, 20.7 KB

    const int tid = threadIdx.x;
    const int lane = tid & 63;
    const int wid = tid >> 6;
    const int k = blockIdx.x >> 1;
    const int h = blockIdx.x & 1;         // which half (chunks 4h .. 4h+3)

    // locate batch via 4-int prefix (batch-major global order)
    int c0 = counts[0], c1 = counts[1], c2 = counts[2];
    int b, base;
    if (k < c0)                { b = 0; base = 0; }
    else if (k < c0 + c1)      { b = 1; base = c0; }
    else if (k < c0 + c1 + c2) { b = 2; base = c0 + c1; }
    else                       { b = 3; base = c0 + c1 + c2; }
    const int info = tinfo[b * TI_STRIDE + (k - base)];
    const int gy0 = info >> 8, gx0 = info & 255;
    if (tid == 0 && h == 0) f_ns[k] = (float)b;

    // zero the chunk buffer once; unoccupied cells stay 0 across all chunks
    const float4 z = make_float4(0.f, 0.f, 0.f, 0.f);
    for (int f4 = tid; f4 < 1296; f4 += 256) ((float4*)s_f)[f4] = z;

    int n = -1;
    if (tid < 81) {
        int r = tid / 9, c = tid - r * 9;
        n = cellmap[b * CMSZ + (gy0 + r) * CMS + (gx0 + c)];
    }
    bool occ = (tid < 81) && (n >= 0);
    unsigned long long bal = __ballot(occ);
    int pre = __popcll(bal & ((1ull << lane) - 1ull));
    if (lane == 0 && wid < 2) s_wcnt[wid] = (int)__popcll(bal);
    __syncthreads();
    if (occ) s_list[(wid == 1 ? s_wcnt[0] : 0) + pre] = (n << 7) | tid;
    if (tid == 0) s_cnt = s_wcnt[0] + s_wcnt[1];
    __syncthreads();

    const int nk = s_cnt;
    const int items = nk * 16;            // float4 gathers per chunk
    const float* __restrict__ fb = feats + (size_t)b * (NN * CC) + h * 256;
    float* __restrict__ outk = out_tiles + (size_t)k * TILE_ELEMS + h * (4 * 64 * 81);

    if (items <= 512) {
        // fast path: <= 2 gather-registers per thread, software-pipelined
        const bool h0 = tid < items, h1 = tid + 256 < items;
        const float* p0 = fb; const float* p1 = fb;
        int d0 = 0, d1 = 0;
        if (h0) { int pk = s_list[tid >> 4], q = tid & 15;
                  p0 = fb + (pk >> 7) * CC + q * 4; d0 = q * 324 + (pk & 127); }
        if (h1) { int e = tid + 256; int pk = s_list[e >> 4], q = e & 15;
                  p1 = fb + (pk >> 7) * CC + q * 4; d1 = q * 324 + (pk & 127); }
        float4 g0, g1;
        if (h0) g0 = *(const float4*)p0;
        if (h1) g1 = *(const float4*)p1;
        #pragma unroll 1
        for (int c = 0; c < 4; ++c) {
            // commit in-flight gathers to LDS (vmcnt wait via data dep)
            if (h0) { s_f[d0] = g0.x; s_f[d0+81] = g0.y; s_f[d0+162] = g0.z; s_f[d0+243] = g0.w; }
            if (h1) { s_f[d1] = g1.x; s_f[d1+81] = g1.y; s_f[d1+162] = g1.z; s_f[d1+243] = g1.w; }
            light_barrier();              // ds_writes visible; stores keep streaming
            // issue next chunk's gathers; they fly under the store stream below
            if (c < 3) {
                if (h0) { p0 += 64; g0 = *(const float4*)p0; }
                if (h1) { p1 += 64; g1 = *(const float4*)p1; }
            }
            // stream chunk c: 1296 float4, conflict-free ds_read_b128, coalesced stores
            float* __restrict__ outc = outk + c * (64 * 81);
            #pragma unroll
            for (int it = 0; it < 6; ++it) {
                int idx = it * 256 + tid;
                if (idx < 1296) {
                    float4 v = ((const float4*)s_f)[idx];
                    *((float4*)outc + idx) = v;
                }
            }
            light_barrier();              // ds_reads done; no store-queue drain
        }
    } else {
        // rare dense-tile fallback (nk > 32): unpipelined
        for (int c = 0; c < 4; ++c) {
            for (int e = tid; e < items; e += 256) {
                int pk = s_list[e >> 4], q = e & 15;
                float4 v = *(const float4*)(fb + (pk >> 7) * CC + c * 64 + q * 4);
                int d = q * 324 + (pk & 127);
                s_f[d] = v.x; s_f[d+81] = v.y; s_f[d+162] = v.z; s_f[d+243] = v.w;
            }
            light_barrier();
            float* __restrict__ outc = outk + c * (64 * 81);
            for (int f4 = tid; f4 < 1296; f4 += 256) {
                float4 v = ((const float4*)s_f)[f4];
                *((float4*)outc + f4) = v;
            }
            light_barrier();
        }
    }
}

extern "C" void kernel_launch(void* const* d_in, const int* in_sizes, int n_in,
                              void* d_out, int out_size, void* d_ws, size_t ws_size,
                              hipStream_t stream) {
    const float* feats = (const float*)d_in[0];
    const int* ys = (const int*)d_in[1];
    const int* xs = (const int*)d_in[2];
    float* out = (float*)d_out;

    char* ws = (char*)d_ws;
    int* cellmap = (int*)ws;                              // 4*132*132*4 = 278784 B
    int* tinfo = (int*)(ws + BB * CMSZ * 4);              // 4*448 ints = 7168 B
    int* counts = (int*)(ws + BB * CMSZ * 4 + BB * TI_STRIDE * 4);  // 4 ints

    const int K = out_size / OUT_PER_TILE;                // number of selected tiles
    float* f_ns = out;                                    // first K floats
    float* out_tiles = out + K;                           // K * 41472 floats

    setup_kernel<<<BB, 512, 0, stream>>>(ys, xs, cellmap, tinfo, counts);
    fill_kernel<<<K * 2, 256, 0, stream>>>(feats, cellmap, tinfo, counts, f_ns, out_tiles);
}